// Round 1
// baseline (134.223 us; speedup 1.0000x reference)
//
#include <hip/hip_runtime.h>
#include <hip/hip_bf16.h>

// Problem: hidden = tanh(x @ (Wi+Wh)^T + (bi+bh)); h_last = hidden[:, T-1, :]
// x: (B,T,C) fp32; Wi,Wh: (H,C) fp32; bi,bh: (H,) fp32. B=16,T=4096,C=H=256.
// GEMM: M=65536, N=256, K=256. Memory-bound (~134MB traffic -> ~21us floor).

using short8 = __attribute__((ext_vector_type(8))) short;
using f32x4  = __attribute__((ext_vector_type(4))) float;

constexpr int Bn = 16, Tn = 4096, Cn = 256, Hn = 256;
constexpr int Mn = Bn * Tn;      // 65536
constexpr int BM = 128, BK = 64; // BN = 256 (full N per block)

// round-to-nearest-even fp32 -> bf16, two at a time, packed into one u32
__device__ inline unsigned pack2_bf16(float a, float b) {
  unsigned ua = __float_as_uint(a);
  unsigned ub = __float_as_uint(b);
  ua += 0x7fffu + ((ua >> 16) & 1u);
  ub += 0x7fffu + ((ub >> 16) & 1u);
  return (ua >> 16) | (ub & 0xffff0000u);
}

__global__ __launch_bounds__(256) void prep_kernel(
    const float* __restrict__ Wi, const float* __restrict__ bi,
    const float* __restrict__ Wh, const float* __restrict__ bh,
    unsigned short* __restrict__ Wc, float* __restrict__ bc) {
  int idx = blockIdx.x * 256 + threadIdx.x;
  float w = Wi[idx] + Wh[idx];
  unsigned u = __float_as_uint(w);
  u += 0x7fffu + ((u >> 16) & 1u);
  Wc[idx] = (unsigned short)(u >> 16);
  if (blockIdx.x == 0) bc[threadIdx.x] = bi[threadIdx.x] + bh[threadIdx.x];
}

// 256 threads = 4 waves; wave (wm,wn) computes 64 rows x 128 cols.
// LDS tiles are stored as 16B chunks with XOR swizzle: chunk' = chunk ^ (row&7)
// -> ds_read_b128 stays 16B-aligned, banks spread (2-way aliasing = free).
__global__ __launch_bounds__(256, 2) void gemm_tanh_kernel(
    const float* __restrict__ x, const unsigned short* __restrict__ Wc,
    const float* __restrict__ bc, float* __restrict__ out) {
  __shared__ __align__(16) unsigned short Asm[BM * BK];   // 16 KB
  __shared__ __align__(16) unsigned short Bsm[256 * BK];  // 32 KB

  const int tid  = threadIdx.x;
  const int lane = tid & 63;
  const int wave = tid >> 6;
  const int wm   = wave >> 1;       // 0..1: m-half (64 rows)
  const int wn   = wave & 1;        // 0..1: n-half (128 cols)
  const int rid  = lane & 15;       // row/col within 16x16 tile
  const int kgrp = lane >> 4;       // 0..3: k-group of 8
  const int mBase = blockIdx.x * BM;

  f32x4 acc[4][8];
#pragma unroll
  for (int i = 0; i < 4; i++)
#pragma unroll
    for (int j = 0; j < 8; j++) acc[i][j] = (f32x4)0.f;

  for (int k0 = 0; k0 < Cn; k0 += BK) {
    // ---- stage A: 128x64 fp32 -> bf16 in LDS. 1024 16B chunks, 4/thread.
#pragma unroll
    for (int i = 0; i < 4; i++) {
      int h = i * 256 + tid;            // 0..1023
      int r = h >> 3;                   // row 0..127
      int c = h & 7;                    // 16B-chunk (8 bf16 = 8 fp32 src)
      const float4* src =
          (const float4*)(x + (size_t)(mBase + r) * Cn + k0) + c * 2;
      float4 v0 = src[0];
      float4 v1 = src[1];
      uint4 p;
      p.x = pack2_bf16(v0.x, v0.y);
      p.y = pack2_bf16(v0.z, v0.w);
      p.z = pack2_bf16(v1.x, v1.y);
      p.w = pack2_bf16(v1.z, v1.w);
      int pc = c ^ (r & 7);
      *(uint4*)&Asm[(r << 6) + (pc << 3)] = p;
    }
    // ---- stage B: 256x64 bf16 from Wc (row-major (N,K) = B^T layout)
#pragma unroll
    for (int i = 0; i < 8; i++) {
      int h = i * 256 + tid;            // 0..2047
      int r = h >> 3;                   // n-row 0..255
      int c = h & 7;
      uint4 v = *(const uint4*)(Wc + r * Cn + k0 + c * 8);
      int pc = c ^ (r & 7);
      *(uint4*)&Bsm[(r << 6) + (pc << 3)] = v;
    }
    __syncthreads();

#pragma unroll
    for (int khalf = 0; khalf < 2; khalf++) {   // two k=32 steps per BK=64
      const int chunk = (khalf << 2) | kgrp;
      short8 af[4], bf[8];
#pragma unroll
      for (int im = 0; im < 4; im++) {
        int row = wm * 64 + im * 16 + rid;
        af[im] = *(const short8*)&Asm[(row << 6) + ((chunk ^ (rid & 7)) << 3)];
      }
#pragma unroll
      for (int in = 0; in < 8; in++) {
        int row = wn * 128 + in * 16 + rid;
        bf[in] = *(const short8*)&Bsm[(row << 6) + ((chunk ^ (rid & 7)) << 3)];
      }
#pragma unroll
      for (int im = 0; im < 4; im++)
#pragma unroll
        for (int in = 0; in < 8; in++)
          acc[im][in] = __builtin_amdgcn_mfma_f32_16x16x32_bf16(
              af[im], bf[in], acc[im][in], 0, 0, 0);
    }
    __syncthreads();
  }

  // ---- epilogue: bias + tanh, write hidden (and h_last rows)
#pragma unroll
  for (int in = 0; in < 8; in++) {
    int n = wn * 128 + in * 16 + rid;
    float bias = bc[n];
#pragma unroll
    for (int im = 0; im < 4; im++) {
      int mrow = mBase + wm * 64 + im * 16 + kgrp * 4;
#pragma unroll
      for (int r = 0; r < 4; r++) {
        int m = mrow + r;
        float v = acc[im][in][r] + bias;
        // tanh(v) = 1 - 2/(exp(2v)+1); exp overflow -> inf -> 1, underflow -> -1
        float t = 1.f - 2.f / (__expf(2.f * v) + 1.f);
        out[(size_t)m * Hn + n] = t;
        if ((m & (Tn - 1)) == (Tn - 1))
          out[(size_t)Mn * Hn + (size_t)(m >> 12) * Hn + n] = t;
      }
    }
  }
}

extern "C" void kernel_launch(void* const* d_in, const int* in_sizes, int n_in,
                              void* d_out, int out_size, void* d_ws,
                              size_t ws_size, hipStream_t stream) {
  (void)in_sizes; (void)n_in; (void)out_size; (void)ws_size;
  const float* x  = (const float*)d_in[0];
  const float* Wi = (const float*)d_in[1];
  const float* bi = (const float*)d_in[2];
  const float* Wh = (const float*)d_in[3];
  const float* bh = (const float*)d_in[4];
  float* out = (float*)d_out;

  unsigned short* Wc = (unsigned short*)d_ws;                       // 128 KB bf16
  float* bc = (float*)((char*)d_ws + (size_t)Hn * Cn * sizeof(unsigned short));

  prep_kernel<<<(Hn * Cn) / 256, 256, 0, stream>>>(Wi, bi, Wh, bh, Wc, bc);
  gemm_tanh_kernel<<<Mn / BM, 256, 0, stream>>>(x, Wc, bc, out);
}